// Round 2
// baseline (120.210 us; speedup 1.0000x reference)
//
#include <hip/hip_runtime.h>
#include <hip/hip_bf16.h>

typedef __bf16 bf16x8 __attribute__((ext_vector_type(8)));
typedef __bf16 bf16x4 __attribute__((ext_vector_type(4)));
typedef float  f32x16 __attribute__((ext_vector_type(16)));
typedef float  f32x4  __attribute__((ext_vector_type(4)));

#define HD     2048   // H*D floats per token row
#define DH     128    // head dim
#define KVB    32     // kv chunk
#define NSPLIT 4
#define NROWS  32768  // Lq*H = 2048*16
#define VSTR   36     // padded stride for V^T tile

// ---------------------------------------------------------------------------
// Attention kernel. SPLIT=true: grid 1024 = 16 qblk x (16 h x 4 split); each
// block handles 16 kv-chunks, writes unnormalized O' + (m,l) to workspace.
// SPLIT=false: grid 256, single pass, writes normalized O directly (ws fallback).
// 256 threads = 4 warps x 32 q-rows.
// ---------------------------------------------------------------------------
template<bool SPLIT>
__global__ __launch_bounds__(256, 1)
void fmha_kern(const float* __restrict__ Qg, const float* __restrict__ Kg,
               const float* __restrict__ Vg, float* __restrict__ outp,
               float* __restrict__ wsML)
{
    __shared__ __align__(16) __bf16 klds[2][32 * 128];     // K chunk, swizzled rows
    __shared__ __align__(16) __bf16 vtlds[2][DH * VSTR];   // V^T chunk [dv][kv]

    const int tid  = threadIdx.x;
    const int lane = tid & 63;
    const int wrp  = tid >> 6;
    const int g    = lane >> 5;   // half-wave
    const int l31  = lane & 31;

    const int b = blockIdx.x;
    int h, qblk, sp, t0, nch;
    if constexpr (SPLIT) {
        // group = b&63 -> XCD = group%8; the 16 qblk-siblings of a (h,split)
        // group land on one XCD and stream the same KV slice -> L2 hits.
        const int grp = b & 63;
        qblk = b >> 6;
        h    = grp >> 2;
        sp   = grp & 3;
        t0   = sp * 16;
        nch  = 16;
    } else {
        h    = 2 * (b & 7) + ((b >> 3) >> 4);
        qblk = (b >> 3) & 15;
        sp   = 0;
        t0   = 0;
        nch  = 64;
    }

    const float qscale = 1.4426950408889634f * 0.08838834764831845f; // log2(e)/sqrt(128)
    const int q = qblk * 128 + wrp * 32 + l31;

    // ---- Q fragments in registers (B-operand of QK^T): lane=q-row, elem e -> d = db*16+8g+e
    bf16x8 qf[8];
    {
        const float* qrow = Qg + (size_t)q * HD + h * DH;
        #pragma unroll
        for (int db = 0; db < 8; ++db) {
            f32x4 a = *(const f32x4*)(qrow + db * 16 + 8 * g);
            f32x4 c = *(const f32x4*)(qrow + db * 16 + 8 * g + 4);
            bf16x8 f;
            f[0] = (__bf16)(a[0] * qscale); f[1] = (__bf16)(a[1] * qscale);
            f[2] = (__bf16)(a[2] * qscale); f[3] = (__bf16)(a[3] * qscale);
            f[4] = (__bf16)(c[0] * qscale); f[5] = (__bf16)(c[1] * qscale);
            f[6] = (__bf16)(c[2] * qscale); f[7] = (__bf16)(c[3] * qscale);
            qf[db] = f;
        }
    }

    // ---- staging work split (256 threads)
    const int krow = tid >> 3, kc = tid & 7;           // K: 32 rows x 8 chunkers
    const int vkv  = tid & 31, vdv0 = (tid >> 5) * 16; // V: 32 kv x 8 dv-slices
    const float* kbase = Kg + (size_t)h * DH;
    const float* vbase = Vg + (size_t)h * DH;

    f32x4 kreg0, kreg1, kreg2, kreg3, vreg0, vreg1, vreg2, vreg3;

    auto stage_load = [&](int t) {   // issue global loads only (T14 issue-early)
        const float* kp = kbase + (size_t)(t * KVB + krow) * HD + kc * 8;
        kreg0 = *(const f32x4*)(kp);
        kreg1 = *(const f32x4*)(kp + 4);
        kreg2 = *(const f32x4*)(kp + 64);
        kreg3 = *(const f32x4*)(kp + 68);
        const float* vp = vbase + (size_t)(t * KVB + vkv) * HD + vdv0;
        vreg0 = *(const f32x4*)(vp);
        vreg1 = *(const f32x4*)(vp + 4);
        vreg2 = *(const f32x4*)(vp + 8);
        vreg3 = *(const f32x4*)(vp + 12);
    };

    auto stage_write = [&](int buf) {  // cvt + LDS write (write-late)
        bf16x8 k0, k1;
        k0[0]=(__bf16)kreg0[0]; k0[1]=(__bf16)kreg0[1]; k0[2]=(__bf16)kreg0[2]; k0[3]=(__bf16)kreg0[3];
        k0[4]=(__bf16)kreg1[0]; k0[5]=(__bf16)kreg1[1]; k0[6]=(__bf16)kreg1[2]; k0[7]=(__bf16)kreg1[3];
        k1[0]=(__bf16)kreg2[0]; k1[1]=(__bf16)kreg2[1]; k1[2]=(__bf16)kreg2[2]; k1[3]=(__bf16)kreg2[3];
        k1[4]=(__bf16)kreg3[0]; k1[5]=(__bf16)kreg3[1]; k1[6]=(__bf16)kreg3[2]; k1[7]=(__bf16)kreg3[3];
        const int swz = (krow & 7) << 3;   // element-units; == byte ^ ((row&7)<<4)
        *(bf16x8*)&klds[buf][krow * 128 + ((kc * 8) ^ swz)]      = k0;
        *(bf16x8*)&klds[buf][krow * 128 + ((kc * 8 + 64) ^ swz)] = k1;
        #pragma unroll
        for (int jj = 0; jj < 4; ++jj) {
            f32x4 vv = (jj == 0) ? vreg0 : (jj == 1) ? vreg1 : (jj == 2) ? vreg2 : vreg3;
            #pragma unroll
            for (int e = 0; e < 4; ++e)
                vtlds[buf][(vdv0 + jj * 4 + e) * VSTR + vkv] = (__bf16)vv[e];
        }
    };

    float mrun = -1e30f, lrun = 0.0f;
    f32x16 o0, o1, o2, o3;
    #pragma unroll
    for (int r = 0; r < 16; ++r) { o0[r] = 0.f; o1[r] = 0.f; o2[r] = 0.f; o3[r] = 0.f; }

    stage_load(t0);
    stage_write(0);

    #pragma unroll 2
    for (int tt = 0; tt < nch; ++tt) {
        const int cur = tt & 1;
        if (tt + 1 < nch) stage_load(t0 + tt + 1);
        __syncthreads();  // buf[cur] writes visible; everyone done reading buf[cur^1]

        // ---- QK^T (swapped): S^T[kv][q], two independent acc chains over d
        f32x16 sa, sb;
        #pragma unroll
        for (int r = 0; r < 16; ++r) { sa[r] = 0.f; sb[r] = 0.f; }
        const int kswz = (l31 & 7) << 3;
        #pragma unroll
        for (int db = 0; db < 4; ++db) {
            bf16x8 kfa = *(const bf16x8*)&klds[cur][l31 * 128 + (((2*db)   * 16 + g * 8) ^ kswz)];
            sa = __builtin_amdgcn_mfma_f32_32x32x16_bf16(kfa, qf[2*db],   sa, 0, 0, 0);
            bf16x8 kfb = *(const bf16x8*)&klds[cur][l31 * 128 + (((2*db+1) * 16 + g * 8) ^ kswz)];
            sb = __builtin_amdgcn_mfma_f32_32x32x16_bf16(kfb, qf[2*db+1], sb, 0, 0, 0);
        }
        f32x16 s;
        #pragma unroll
        for (int r = 0; r < 16; ++r) s[r] = sa[r] + sb[r];

        // ---- online softmax, T13 defer-max (base-2 domain, P bounded by 2^8)
        float m8[8];
        #pragma unroll
        for (int r = 0; r < 8; ++r) m8[r] = fmaxf(s[r], s[r + 8]);
        float tmax = fmaxf(fmaxf(fmaxf(m8[0], m8[4]), fmaxf(m8[1], m8[5])),
                           fmaxf(fmaxf(m8[2], m8[6]), fmaxf(m8[3], m8[7])));
        tmax = fmaxf(tmax, __shfl_xor(tmax, 32, 64));

        if (__any(tmax > mrun + 8.0f)) {
            const float mnew  = fmaxf(mrun, tmax);
            const float alpha = __builtin_amdgcn_exp2f(mrun - mnew);
            lrun *= alpha;
            #pragma unroll
            for (int r = 0; r < 16; ++r) { o0[r] *= alpha; o1[r] *= alpha; o2[r] *= alpha; o3[r] *= alpha; }
            mrun = mnew;
        }

        float p[16];
        #pragma unroll
        for (int r = 0; r < 16; ++r) p[r] = __builtin_amdgcn_exp2f(s[r] - mrun);
        float ps0 = 0, ps1 = 0, ps2 = 0, ps3 = 0;
        #pragma unroll
        for (int r = 0; r < 4; ++r) { ps0 += p[r]; ps1 += p[r+4]; ps2 += p[r+8]; ps3 += p[r+12]; }
        lrun += ((ps0 + ps1) + (ps2 + ps3));

        // P -> bf16 fragments; S^T C/D reg order == PV B-operand slot order (same k bijection)
        bf16x8 pf0, pf1;
        #pragma unroll
        for (int e = 0; e < 8; ++e) { pf0[e] = (__bf16)p[e]; pf1[e] = (__bf16)p[8 + e]; }

        // ---- PV: O^T[dv][q] += V^T[dv][kv] * P^T[kv][q], 4 dv-blocks x 2 kv-halves
        #pragma unroll
        for (int bb = 0; bb < 4; ++bb) {
            const __bf16* vb = &vtlds[cur][(bb * 32 + l31) * VSTR];
            bf16x4 a0 = *(const bf16x4*)(vb + 4 * g);
            bf16x4 a1 = *(const bf16x4*)(vb + 8 + 4 * g);
            bf16x8 va;
            va[0]=a0[0]; va[1]=a0[1]; va[2]=a0[2]; va[3]=a0[3];
            va[4]=a1[0]; va[5]=a1[1]; va[6]=a1[2]; va[7]=a1[3];
            f32x16& oo = (bb == 0) ? o0 : (bb == 1) ? o1 : (bb == 2) ? o2 : o3;
            oo = __builtin_amdgcn_mfma_f32_32x32x16_bf16(va, pf0, oo, 0, 0, 0);
            bf16x4 b0 = *(const bf16x4*)(vb + 16 + 4 * g);
            bf16x4 b1 = *(const bf16x4*)(vb + 24 + 4 * g);
            va[0]=b0[0]; va[1]=b0[1]; va[2]=b0[2]; va[3]=b0[3];
            va[4]=b1[0]; va[5]=b1[1]; va[6]=b1[2]; va[7]=b1[3];
            oo = __builtin_amdgcn_mfma_f32_32x32x16_bf16(va, pf1, oo, 0, 0, 0);
        }

        if (tt + 1 < nch) stage_write(cur ^ 1);
    }

    // ---- epilogue
    const float ltot  = lrun + __shfl_xor(lrun, 32, 64);
    const int   rowid = q * 16 + h;   // output row index (q,h)

    if constexpr (SPLIT) {
        float* orow = outp + ((size_t)sp * NROWS + rowid) * 128;
        #pragma unroll
        for (int bb = 0; bb < 4; ++bb) {
            const f32x16& oo = (bb == 0) ? o0 : (bb == 1) ? o1 : (bb == 2) ? o2 : o3;
            #pragma unroll
            for (int jj = 0; jj < 4; ++jj) {
                f32x4 v;
                v[0] = oo[4*jj+0]; v[1] = oo[4*jj+1]; v[2] = oo[4*jj+2]; v[3] = oo[4*jj+3];
                *(f32x4*)(orow + bb * 32 + 8 * jj + 4 * g) = v;
            }
        }
        if (lane < 32) {
            float* ml = wsML + ((size_t)sp * NROWS + rowid) * 2;
            ml[0] = mrun;
            ml[1] = ltot;
        }
    } else {
        const float inv = 1.0f / ltot;
        float* orow = outp + (size_t)rowid * 128;
        #pragma unroll
        for (int bb = 0; bb < 4; ++bb) {
            const f32x16& oo = (bb == 0) ? o0 : (bb == 1) ? o1 : (bb == 2) ? o2 : o3;
            #pragma unroll
            for (int jj = 0; jj < 4; ++jj) {
                f32x4 v;
                v[0] = oo[4*jj+0] * inv; v[1] = oo[4*jj+1] * inv;
                v[2] = oo[4*jj+2] * inv; v[3] = oo[4*jj+3] * inv;
                *(f32x4*)(orow + bb * 32 + 8 * jj + 4 * g) = v;
            }
        }
    }
}

// ---------------------------------------------------------------------------
// Combine kernel: O[row] = sum_s 2^(m_s - M) * O'_s[row] / L,
// L = sum_s l_s 2^(m_s - M). 256 threads = 8 rows x 32 lanes x f32x4.
// ---------------------------------------------------------------------------
__global__ __launch_bounds__(256, 1)
void fmha_combine(const float* __restrict__ wsO, const float* __restrict__ wsML,
                  float* __restrict__ Og)
{
    const int tid   = threadIdx.x;
    const int rowid = blockIdx.x * 8 + (tid >> 5);
    const int c     = (tid & 31) * 4;

    float m[NSPLIT], l[NSPLIT];
    float M = -1e30f;
    #pragma unroll
    for (int s = 0; s < NSPLIT; ++s) {
        const float* ml = wsML + ((size_t)s * NROWS + rowid) * 2;
        m[s] = ml[0];
        l[s] = ml[1];
        M = fmaxf(M, m[s]);
    }
    float L = 0.f, w[NSPLIT];
    #pragma unroll
    for (int s = 0; s < NSPLIT; ++s) {
        w[s] = __builtin_amdgcn_exp2f(m[s] - M);
        L += l[s] * w[s];
    }
    const float inv = 1.0f / L;

    f32x4 acc; acc[0] = 0.f; acc[1] = 0.f; acc[2] = 0.f; acc[3] = 0.f;
    #pragma unroll
    for (int s = 0; s < NSPLIT; ++s) {
        f32x4 v = *(const f32x4*)(wsO + ((size_t)s * NROWS + rowid) * 128 + c);
        acc[0] += v[0] * w[s]; acc[1] += v[1] * w[s];
        acc[2] += v[2] * w[s]; acc[3] += v[3] * w[s];
    }
    f32x4 r;
    r[0] = acc[0] * inv; r[1] = acc[1] * inv; r[2] = acc[2] * inv; r[3] = acc[3] * inv;
    *(f32x4*)(Og + (size_t)rowid * 128 + c) = r;
}

extern "C" void kernel_launch(void* const* d_in, const int* in_sizes, int n_in,
                              void* d_out, int out_size, void* d_ws, size_t ws_size,
                              hipStream_t stream) {
    const float* Q = (const float*)d_in[0];
    const float* K = (const float*)d_in[1];
    const float* V = (const float*)d_in[2];
    float* O = (float*)d_out;

    const size_t needO  = (size_t)NSPLIT * NROWS * 128;      // floats
    const size_t needML = (size_t)NSPLIT * NROWS * 2;        // floats
    const size_t need_bytes = (needO + needML) * sizeof(float);

    if (ws_size >= need_bytes) {
        float* wsO  = (float*)d_ws;
        float* wsML = wsO + needO;
        hipLaunchKernelGGL(fmha_kern<true>, dim3(1024), dim3(256), 0, stream,
                           Q, K, V, wsO, wsML);
        hipLaunchKernelGGL(fmha_combine, dim3(NROWS / 8), dim3(256), 0, stream,
                           wsO, wsML, O);
    } else {
        hipLaunchKernelGGL(fmha_kern<false>, dim3(256), dim3(256), 0, stream,
                           Q, K, V, O, (float*)nullptr);
    }
}

// Round 3
// 73.009 us; speedup vs baseline: 1.6465x; 1.6465x over previous
//
#include <hip/hip_runtime.h>
#include <hip/hip_bf16.h>

typedef __bf16 bf16x8 __attribute__((ext_vector_type(8)));
typedef __bf16 bf16x4 __attribute__((ext_vector_type(4)));
typedef float  f32x16 __attribute__((ext_vector_type(16)));
typedef float  f32x4  __attribute__((ext_vector_type(4)));

#define HD     2048   // H*D floats per token row
#define DH     128    // head dim
#define KVB    32     // kv chunk
#define NSPLIT 2
#define NROWS  32768  // Lq*H = 2048*16
#define VSTR   36     // padded stride for V^T tile

// ---------------------------------------------------------------------------
// Attention kernel. SPLIT=true: grid 512 = 16 qblk x (16 h x 2 split); each
// block handles 32 kv-chunks, writes unnormalized O' + (m,l) to workspace.
// SPLIT=false: grid 256, single pass (ws fallback).
// 256 threads = 4 warps x 32 q-rows. launch_bounds(256,2): cap total
// VGPR+AGPR <= 256 so 2 waves/SIMD (2 blocks/CU) co-reside — R2 showed
// (256,1) let the allocator exceed 256 and pinned occupancy at 1 wave/SIMD.
// ---------------------------------------------------------------------------
template<bool SPLIT>
__global__ __launch_bounds__(256, 2)
void fmha_kern(const float* __restrict__ Qg, const float* __restrict__ Kg,
               const float* __restrict__ Vg, float* __restrict__ outp,
               float* __restrict__ wsML)
{
    __shared__ __align__(16) __bf16 klds[2][32 * 128];     // K chunk, swizzled rows
    __shared__ __align__(16) __bf16 vtlds[2][DH * VSTR];   // V^T chunk [dv][kv]

    const int tid  = threadIdx.x;
    const int lane = tid & 63;
    const int wrp  = tid >> 6;
    const int g    = lane >> 5;   // half-wave
    const int l31  = lane & 31;

    const int b = blockIdx.x;
    int h, qblk, sp, t0, nch;
    if constexpr (SPLIT) {
        // b = qblk*32 + grp, grp = h*2+sp. XCD = b%8 = grp%8 -> all 16
        // qblk-siblings of one (h,sp) group land on one XCD (shared KV in L2).
        const int grp = b & 31;
        qblk = b >> 5;
        h    = grp >> 1;
        sp   = grp & 1;
        t0   = sp * 32;
        nch  = 32;
    } else {
        h    = 2 * (b & 7) + ((b >> 3) >> 4);
        qblk = (b >> 3) & 15;
        sp   = 0;
        t0   = 0;
        nch  = 64;
    }

    const float qscale = 1.4426950408889634f * 0.08838834764831845f; // log2(e)/sqrt(128)
    const int q = qblk * 128 + wrp * 32 + l31;

    // ---- Q fragments in registers (B-operand of QK^T): lane=q-row, elem e -> d = db*16+8g+e
    bf16x8 qf[8];
    {
        const float* qrow = Qg + (size_t)q * HD + h * DH;
        #pragma unroll
        for (int db = 0; db < 8; ++db) {
            f32x4 a = *(const f32x4*)(qrow + db * 16 + 8 * g);
            f32x4 c = *(const f32x4*)(qrow + db * 16 + 8 * g + 4);
            bf16x8 f;
            f[0] = (__bf16)(a[0] * qscale); f[1] = (__bf16)(a[1] * qscale);
            f[2] = (__bf16)(a[2] * qscale); f[3] = (__bf16)(a[3] * qscale);
            f[4] = (__bf16)(c[0] * qscale); f[5] = (__bf16)(c[1] * qscale);
            f[6] = (__bf16)(c[2] * qscale); f[7] = (__bf16)(c[3] * qscale);
            qf[db] = f;
        }
    }

    // ---- staging work split (256 threads)
    const int krow = tid >> 3, kc = tid & 7;           // K: 32 rows x 8 chunkers
    const int vkv  = tid & 31, vdv0 = (tid >> 5) * 16; // V: 32 kv x 8 dv-slices
    const float* kbase = Kg + (size_t)h * DH;
    const float* vbase = Vg + (size_t)h * DH;

    f32x4 kreg0, kreg1, kreg2, kreg3, vreg0, vreg1, vreg2, vreg3;

    auto stage_load = [&](int t) {   // issue global loads only (T14 issue-early)
        const float* kp = kbase + (size_t)(t * KVB + krow) * HD + kc * 8;
        kreg0 = *(const f32x4*)(kp);
        kreg1 = *(const f32x4*)(kp + 4);
        kreg2 = *(const f32x4*)(kp + 64);
        kreg3 = *(const f32x4*)(kp + 68);
        const float* vp = vbase + (size_t)(t * KVB + vkv) * HD + vdv0;
        vreg0 = *(const f32x4*)(vp);
        vreg1 = *(const f32x4*)(vp + 4);
        vreg2 = *(const f32x4*)(vp + 8);
        vreg3 = *(const f32x4*)(vp + 12);
    };

    auto stage_write = [&](int buf) {  // cvt + LDS write (write-late)
        bf16x8 k0, k1;
        k0[0]=(__bf16)kreg0[0]; k0[1]=(__bf16)kreg0[1]; k0[2]=(__bf16)kreg0[2]; k0[3]=(__bf16)kreg0[3];
        k0[4]=(__bf16)kreg1[0]; k0[5]=(__bf16)kreg1[1]; k0[6]=(__bf16)kreg1[2]; k0[7]=(__bf16)kreg1[3];
        k1[0]=(__bf16)kreg2[0]; k1[1]=(__bf16)kreg2[1]; k1[2]=(__bf16)kreg2[2]; k1[3]=(__bf16)kreg2[3];
        k1[4]=(__bf16)kreg3[0]; k1[5]=(__bf16)kreg3[1]; k1[6]=(__bf16)kreg3[2]; k1[7]=(__bf16)kreg3[3];
        const int swz = (krow & 7) << 3;   // element-units; == byte ^ ((row&7)<<4)
        *(bf16x8*)&klds[buf][krow * 128 + ((kc * 8) ^ swz)]      = k0;
        *(bf16x8*)&klds[buf][krow * 128 + ((kc * 8 + 64) ^ swz)] = k1;
        #pragma unroll
        for (int jj = 0; jj < 4; ++jj) {
            f32x4 vv = (jj == 0) ? vreg0 : (jj == 1) ? vreg1 : (jj == 2) ? vreg2 : vreg3;
            #pragma unroll
            for (int e = 0; e < 4; ++e)
                vtlds[buf][(vdv0 + jj * 4 + e) * VSTR + vkv] = (__bf16)vv[e];
        }
    };

    float mrun = -1e30f, lrun = 0.0f;
    f32x16 o0, o1, o2, o3;
    #pragma unroll
    for (int r = 0; r < 16; ++r) { o0[r] = 0.f; o1[r] = 0.f; o2[r] = 0.f; o3[r] = 0.f; }

    stage_load(t0);
    stage_write(0);

    #pragma unroll 2
    for (int tt = 0; tt < nch; ++tt) {
        const int cur = tt & 1;
        if (tt + 1 < nch) stage_load(t0 + tt + 1);
        __syncthreads();  // buf[cur] writes visible; everyone done reading buf[cur^1]

        // ---- QK^T (swapped): S^T[kv][q], two independent acc chains over d
        f32x16 sa, sb;
        #pragma unroll
        for (int r = 0; r < 16; ++r) { sa[r] = 0.f; sb[r] = 0.f; }
        const int kswz = (l31 & 7) << 3;
        #pragma unroll
        for (int db = 0; db < 4; ++db) {
            bf16x8 kfa = *(const bf16x8*)&klds[cur][l31 * 128 + (((2*db)   * 16 + g * 8) ^ kswz)];
            sa = __builtin_amdgcn_mfma_f32_32x32x16_bf16(kfa, qf[2*db],   sa, 0, 0, 0);
            bf16x8 kfb = *(const bf16x8*)&klds[cur][l31 * 128 + (((2*db+1) * 16 + g * 8) ^ kswz)];
            sb = __builtin_amdgcn_mfma_f32_32x32x16_bf16(kfb, qf[2*db+1], sb, 0, 0, 0);
        }
        f32x16 s;
        #pragma unroll
        for (int r = 0; r < 16; ++r) s[r] = sa[r] + sb[r];

        // ---- online softmax, T13 defer-max (base-2 domain, P bounded by 2^8)
        float m8[8];
        #pragma unroll
        for (int r = 0; r < 8; ++r) m8[r] = fmaxf(s[r], s[r + 8]);
        float tmax = fmaxf(fmaxf(fmaxf(m8[0], m8[4]), fmaxf(m8[1], m8[5])),
                           fmaxf(fmaxf(m8[2], m8[6]), fmaxf(m8[3], m8[7])));
        tmax = fmaxf(tmax, __shfl_xor(tmax, 32, 64));

        if (__any(tmax > mrun + 8.0f)) {
            const float mnew  = fmaxf(mrun, tmax);
            const float alpha = __builtin_amdgcn_exp2f(mrun - mnew);
            lrun *= alpha;
            #pragma unroll
            for (int r = 0; r < 16; ++r) { o0[r] *= alpha; o1[r] *= alpha; o2[r] *= alpha; o3[r] *= alpha; }
            mrun = mnew;
        }

        float p[16];
        #pragma unroll
        for (int r = 0; r < 16; ++r) p[r] = __builtin_amdgcn_exp2f(s[r] - mrun);
        float ps0 = 0, ps1 = 0, ps2 = 0, ps3 = 0;
        #pragma unroll
        for (int r = 0; r < 4; ++r) { ps0 += p[r]; ps1 += p[r+4]; ps2 += p[r+8]; ps3 += p[r+12]; }
        lrun += ((ps0 + ps1) + (ps2 + ps3));

        // P -> bf16 fragments; S^T C/D reg order == PV B-operand slot order (same k bijection)
        bf16x8 pf0, pf1;
        #pragma unroll
        for (int e = 0; e < 8; ++e) { pf0[e] = (__bf16)p[e]; pf1[e] = (__bf16)p[8 + e]; }

        // ---- PV: O^T[dv][q] += V^T[dv][kv] * P^T[kv][q], 4 dv-blocks x 2 kv-halves
        #pragma unroll
        for (int bb = 0; bb < 4; ++bb) {
            const __bf16* vb = &vtlds[cur][(bb * 32 + l31) * VSTR];
            bf16x4 a0 = *(const bf16x4*)(vb + 4 * g);
            bf16x4 a1 = *(const bf16x4*)(vb + 8 + 4 * g);
            bf16x8 va;
            va[0]=a0[0]; va[1]=a0[1]; va[2]=a0[2]; va[3]=a0[3];
            va[4]=a1[0]; va[5]=a1[1]; va[6]=a1[2]; va[7]=a1[3];
            f32x16& oo = (bb == 0) ? o0 : (bb == 1) ? o1 : (bb == 2) ? o2 : o3;
            oo = __builtin_amdgcn_mfma_f32_32x32x16_bf16(va, pf0, oo, 0, 0, 0);
            bf16x4 b0 = *(const bf16x4*)(vb + 16 + 4 * g);
            bf16x4 b1 = *(const bf16x4*)(vb + 24 + 4 * g);
            va[0]=b0[0]; va[1]=b0[1]; va[2]=b0[2]; va[3]=b0[3];
            va[4]=b1[0]; va[5]=b1[1]; va[6]=b1[2]; va[7]=b1[3];
            oo = __builtin_amdgcn_mfma_f32_32x32x16_bf16(va, pf1, oo, 0, 0, 0);
        }

        if (tt + 1 < nch) stage_write(cur ^ 1);
    }

    // ---- epilogue
    const float ltot  = lrun + __shfl_xor(lrun, 32, 64);
    const int   rowid = q * 16 + h;   // output row index (q,h)

    if constexpr (SPLIT) {
        float* orow = outp + ((size_t)sp * NROWS + rowid) * 128;
        #pragma unroll
        for (int bb = 0; bb < 4; ++bb) {
            const f32x16& oo = (bb == 0) ? o0 : (bb == 1) ? o1 : (bb == 2) ? o2 : o3;
            #pragma unroll
            for (int jj = 0; jj < 4; ++jj) {
                f32x4 v;
                v[0] = oo[4*jj+0]; v[1] = oo[4*jj+1]; v[2] = oo[4*jj+2]; v[3] = oo[4*jj+3];
                *(f32x4*)(orow + bb * 32 + 8 * jj + 4 * g) = v;
            }
        }
        if (lane < 32) {
            float* ml = wsML + ((size_t)sp * NROWS + rowid) * 2;
            ml[0] = mrun;
            ml[1] = ltot;
        }
    } else {
        const float inv = 1.0f / ltot;
        float* orow = outp + (size_t)rowid * 128;
        #pragma unroll
        for (int bb = 0; bb < 4; ++bb) {
            const f32x16& oo = (bb == 0) ? o0 : (bb == 1) ? o1 : (bb == 2) ? o2 : o3;
            #pragma unroll
            for (int jj = 0; jj < 4; ++jj) {
                f32x4 v;
                v[0] = oo[4*jj+0] * inv; v[1] = oo[4*jj+1] * inv;
                v[2] = oo[4*jj+2] * inv; v[3] = oo[4*jj+3] * inv;
                *(f32x4*)(orow + bb * 32 + 8 * jj + 4 * g) = v;
            }
        }
    }
}

// ---------------------------------------------------------------------------
// Combine kernel: O[row] = sum_s 2^(m_s - M) * O'_s[row] / L.
// 256 threads = 8 rows x 32 lanes x f32x4.
// ---------------------------------------------------------------------------
__global__ __launch_bounds__(256, 4)
void fmha_combine(const float* __restrict__ wsO, const float* __restrict__ wsML,
                  float* __restrict__ Og)
{
    const int tid   = threadIdx.x;
    const int rowid = blockIdx.x * 8 + (tid >> 5);
    const int c     = (tid & 31) * 4;

    float m[NSPLIT], l[NSPLIT];
    float M = -1e30f;
    #pragma unroll
    for (int s = 0; s < NSPLIT; ++s) {
        const float* ml = wsML + ((size_t)s * NROWS + rowid) * 2;
        m[s] = ml[0];
        l[s] = ml[1];
        M = fmaxf(M, m[s]);
    }
    float L = 0.f, w[NSPLIT];
    #pragma unroll
    for (int s = 0; s < NSPLIT; ++s) {
        w[s] = __builtin_amdgcn_exp2f(m[s] - M);
        L += l[s] * w[s];
    }
    const float inv = 1.0f / L;

    f32x4 acc; acc[0] = 0.f; acc[1] = 0.f; acc[2] = 0.f; acc[3] = 0.f;
    #pragma unroll
    for (int s = 0; s < NSPLIT; ++s) {
        f32x4 v = *(const f32x4*)(wsO + ((size_t)s * NROWS + rowid) * 128 + c);
        acc[0] += v[0] * w[s]; acc[1] += v[1] * w[s];
        acc[2] += v[2] * w[s]; acc[3] += v[3] * w[s];
    }
    f32x4 r;
    r[0] = acc[0] * inv; r[1] = acc[1] * inv; r[2] = acc[2] * inv; r[3] = acc[3] * inv;
    *(f32x4*)(Og + (size_t)rowid * 128 + c) = r;
}

extern "C" void kernel_launch(void* const* d_in, const int* in_sizes, int n_in,
                              void* d_out, int out_size, void* d_ws, size_t ws_size,
                              hipStream_t stream) {
    const float* Q = (const float*)d_in[0];
    const float* K = (const float*)d_in[1];
    const float* V = (const float*)d_in[2];
    float* O = (float*)d_out;

    const size_t needO  = (size_t)NSPLIT * NROWS * 128;      // floats
    const size_t needML = (size_t)NSPLIT * NROWS * 2;        // floats
    const size_t need_bytes = (needO + needML) * sizeof(float);

    if (ws_size >= need_bytes) {
        float* wsO  = (float*)d_ws;
        float* wsML = wsO + needO;
        hipLaunchKernelGGL(fmha_kern<true>, dim3(512), dim3(256), 0, stream,
                           Q, K, V, wsO, wsML);
        hipLaunchKernelGGL(fmha_combine, dim3(NROWS / 8), dim3(256), 0, stream,
                           wsO, wsML, O);
    } else {
        hipLaunchKernelGGL(fmha_kern<false>, dim3(256), dim3(256), 0, stream,
                           Q, K, V, O, (float*)nullptr);
    }
}